// Round 6
// baseline (189.680 us; speedup 1.0000x reference)
//
#include <hip/hip_runtime.h>

// AutoEncoderLoss: two-level segment-mean MSE over seg = b*128 + c.
// R6: LDS atomics eliminated (measured: LDS atomic adds ~3cy/lane/CU,
// serialized -> 41us hard floor at 1 atomic/elem). Replaced with one-hot
// MFMA histogram: c = hi*16+lo; key = hi + 8*rel (rel = batch - b0, folds
// the sorted-batch boundary into C rows 8..15).
//   A[row][k] = sq_k (bf16) * (key_k == row);  B[k][col] = (lo_k == col)
//   C_sum = A.B gives all 2x128 segment sums; second MFMA with A=indicator
//   gives counts. Layouts per m89/m91/m120: A/B lane&15=row/col, k=quad*8+j;
//   C col=lane&15, row=quad*4+reg.
// K2: 32x1024 sliced row-sum over per-block scratch (float2). K3: combine.

#define BATCHES 32
#define CLUSTERS 128
#define NSEG (BATCHES * CLUSTERS)
#define BLOCK 256
#define EPB 4096
#define SLICES 8

typedef unsigned int u32;
typedef __attribute__((ext_vector_type(8))) short short8;
typedef __attribute__((ext_vector_type(4))) float floatx4;

__device__ __forceinline__ unsigned short f32_to_bf16(float f) {
    u32 x = __builtin_bit_cast(u32, f);
    x += 0x7fffu + ((x >> 16) & 1u);   // RNE; inputs finite
    return (unsigned short)(x >> 16);
}

__device__ __forceinline__ u32 pack_elem(float r, float t, int c, int rel) {
    const float d = r - t;
    return (u32)f32_to_bf16(d * d)
         | ((u32)(c & 15) << 16)
         | ((u32)((c >> 4) + 8 * rel) << 20);
}

__global__ __launch_bounds__(BLOCK, 8) void mfma_accum_kernel(
    const float* __restrict__ reco,
    const float* __restrict__ target,
    const int* __restrict__ clabel,
    const int* __restrict__ batch_index,
    float2* __restrict__ scratch,   // [gridDim.x * 256] (sum,cnt) per (rel,c)
    int* __restrict__ b0_arr,       // [gridDim.x]
    float* __restrict__ oseg,       // [NSEG*2] overflow (sum,cnt), zeroed
    int n)
{
    __shared__ u32 pk[EPB];   // 16 KB staging; reused as 8 KB reduce buffer
    const int tid = threadIdx.x;
    const long long base = (long long)blockIdx.x * EPB;
    if (base >= n) { if (tid == 0) b0_arr[blockIdx.x] = 0x7fffffff; return; }
    const long long lim = (base + EPB <= (long long)n) ? base + EPB : (long long)n;
    const int b0 = batch_index[base];
    const int bL = batch_index[lim - 1];
    if (tid == 0) b0_arr[blockIdx.x] = b0;

    // Block-uniform fallback: partial tail chunk or span > 2 batches
    // (never for N=2^23, B-sizes ~262k; correctness guard only).
    if ((bL - b0 > 1) || (lim - base < EPB)) {
        for (int e = tid; e < 2 * CLUSTERS; e += BLOCK)
            scratch[(long long)blockIdx.x * 2 * CLUSTERS + e] = make_float2(0.f, 0.f);
        for (long long i = base + tid; i < lim; i += BLOCK) {
            const float d = reco[i] - target[i];
            const int seg = batch_index[i] * CLUSTERS + clabel[i];
            atomicAdd(&oseg[2 * seg],     d * d);
            atomicAdd(&oseg[2 * seg + 1], 1.0f);
        }
        return;
    }

    // ---- Phase 1: stage packed elements (sq_bf16 | lo<<16 | key<<20) ----
    const bool boundary = (bL != b0);
    #pragma unroll
    for (int k = 0; k < 4; ++k) {
        const long long idx = base + (long long)(k * BLOCK + tid) * 4;
        const float4 r = *(const float4*)(reco + idx);
        const float4 t = *(const float4*)(target + idx);
        const int4   c = *(const int4*)(clabel + idx);
        int rx = 0, ry = 0, rz = 0, rw = 0;
        if (boundary) {
            const int4 b = *(const int4*)(batch_index + idx);
            rx = b.x - b0; ry = b.y - b0; rz = b.z - b0; rw = b.w - b0;
        }
        uint4 o;
        o.x = pack_elem(r.x, t.x, c.x, rx);
        o.y = pack_elem(r.y, t.y, c.y, ry);
        o.z = pack_elem(r.z, t.z, c.z, rz);
        o.w = pack_elem(r.w, t.w, c.w, rw);
        *(uint4*)&pk[(k * BLOCK + tid) * 4] = o;
    }
    __syncthreads();

    // ---- Phase 2: one-hot MFMA over 32 chunks of 32 elements per wave ----
    const int lane = tid & 63;
    const int wave = tid >> 6;
    const int quad = lane >> 4;     // k-group: k = quad*8 + j
    const int rc   = lane & 15;     // A row / B col this lane builds
    floatx4 accS = {0.f, 0.f, 0.f, 0.f};
    floatx4 accC = {0.f, 0.f, 0.f, 0.f};
    const u32* wbase = pk + wave * 1024;

    for (int ch = 0; ch < 32; ++ch) {
        const uint4 pa = *(const uint4*)(wbase + ch * 32 + quad * 8);
        const uint4 pb = *(const uint4*)(wbase + ch * 32 + quad * 8 + 4);
        const u32 p[8] = {pa.x, pa.y, pa.z, pa.w, pb.x, pb.y, pb.z, pb.w};
        short8 aS, aC, bB;
        #pragma unroll
        for (int j = 0; j < 8; ++j) {
            const u32 pj = p[j];
            const bool mA = (int)((pj >> 20) & 15u) == rc;
            const bool mB = (int)((pj >> 16) & 15u) == rc;
            aS[j] = mA ? (short)(pj & 0xffffu) : (short)0;
            aC[j] = mA ? (short)0x3f80 : (short)0;   // bf16 1.0
            bB[j] = mB ? (short)0x3f80 : (short)0;
        }
        accS = __builtin_amdgcn_mfma_f32_16x16x32_bf16(aS, bB, accS, 0, 0, 0);
        accC = __builtin_amdgcn_mfma_f32_16x16x32_bf16(aC, bB, accC, 0, 0, 0);
    }
    __syncthreads();   // all chunk reads done before reusing pk

    // ---- Epilogue: cross-wave reduce in LDS, write block scratch row ----
    float* red = (float*)pk;   // [wave][{sum,cnt}][256]
    #pragma unroll
    for (int g = 0; g < 4; ++g) {
        const int row = quad * 4 + g;          // C: col=lane&15, row=quad*4+g
        red[wave * 512 +       row * 16 + rc] = accS[g];
        red[wave * 512 + 256 + row * 16 + rc] = accC[g];
    }
    __syncthreads();
    {
        const int e = tid;                     // 0..255 = row*16+col
        const int row = e >> 4, col = e & 15;
        const float s   = red[e]       + red[512 + e]        + red[1024 + e]        + red[1536 + e];
        const float cnt = red[256 + e] + red[512 + 256 + e]  + red[1024 + 256 + e]  + red[1536 + 256 + e];
        const int idx = (row >> 3) * CLUSTERS + (row & 7) * 16 + col;  // rel*128 + hi*16 + lo
        scratch[(long long)blockIdx.x * 2 * CLUSTERS + idx] = make_float2(s, cnt);
    }
}

__global__ __launch_bounds__(1024) void batch_reduce_kernel(
    const float2* __restrict__ scratch,
    const int* __restrict__ b0_arr,
    const float* __restrict__ oseg,
    float* __restrict__ bl,      // [BATCHES]
    float* __restrict__ bp,      // [BATCHES]
    int nblocks)
{
    __shared__ float2 part[SLICES][CLUSTERS];
    __shared__ float ssm[2], snp[2];
    const int b     = blockIdx.x;
    const int tid   = threadIdx.x;
    const int slice = tid >> 7;
    const int c     = tid & (CLUSTERS - 1);

    int lo = 0, hi = nblocks;
    while (lo < hi) { const int m = (lo + hi) >> 1; if (b0_arr[m] < b - 1) lo = m + 1; else hi = m; }
    int lo2 = lo, hi2 = nblocks;
    while (lo2 < hi2) { const int m = (lo2 + hi2) >> 1; if (b0_arr[m] < b + 1) lo2 = m + 1; else hi2 = m; }

    float2 acc = make_float2(0.f, 0.f);
    for (int j = lo + slice; j < lo2; j += SLICES) {
        const int off = (b0_arr[j] == b) ? c : (CLUSTERS + c);
        const float2 v = scratch[(long long)j * 2 * CLUSTERS + off];
        acc.x += v.x; acc.y += v.y;
    }
    part[slice][c] = acc;
    __syncthreads();

    if (tid < CLUSTERS) {
        float s   = oseg[2 * (b * CLUSTERS + tid)];
        float cnt = oseg[2 * (b * CLUSTERS + tid) + 1];
        #pragma unroll
        for (int sl = 0; sl < SLICES; ++sl) { s += part[sl][tid].x; cnt += part[sl][tid].y; }
        float sm = 0.f, np = 0.f;
        if (cnt > 0.5f) { sm = s / cnt; np = 1.f; }
        #pragma unroll
        for (int off = 32; off; off >>= 1) {
            sm += __shfl_down(sm, off);
            np += __shfl_down(np, off);
        }
        if ((tid & 63) == 0) { ssm[tid >> 6] = sm; snp[tid >> 6] = np; }
    }
    __syncthreads();
    if (tid == 0) {
        const float S = ssm[0] + ssm[1];
        const float P = snp[0] + snp[1];
        bl[b] = (P > 0.f) ? (S / P) : 0.f;
        bp[b] = (P > 0.f) ? 1.f : 0.f;
    }
}

__global__ __launch_bounds__(64) void final_kernel(
    const float* __restrict__ bl,
    const float* __restrict__ bp,
    float* __restrict__ out)
{
    const int t = threadIdx.x;
    float s = 0.f, nb = 0.f;
    if (t < BATCHES) { s = bl[t]; nb = bp[t]; }
    #pragma unroll
    for (int off = 16; off; off >>= 1) {
        s  += __shfl_down(s, off, 32);
        nb += __shfl_down(nb, off, 32);
    }
    if (t == 0) out[0] = (nb > 0.f) ? (s / nb) : 0.f;
}

extern "C" void kernel_launch(void* const* d_in, const int* in_sizes, int n_in,
                              void* d_out, int out_size, void* d_ws, size_t ws_size,
                              hipStream_t stream) {
    const float* reco        = (const float*)d_in[0];
    const float* target      = (const float*)d_in[1];
    const int*   clabel      = (const int*)d_in[2];
    const int*   batch_index = (const int*)d_in[3];
    const int n = in_sizes[0];
    const int nblocks = (n + EPB - 1) / EPB;

    char*   ws      = (char*)d_ws;
    float*  oseg    = (float*)ws;                                 // 32 KB, memset
    int*    b0_arr  = (int*)(ws + NSEG * 2 * sizeof(float));      // fully written by K1
    size_t  b0_bytes = ((size_t)nblocks * sizeof(int) + 255) & ~(size_t)255;
    float2* scratch = (float2*)(ws + NSEG * 2 * sizeof(float) + b0_bytes);  // fully written
    float*  bl      = (float*)((char*)scratch + (size_t)nblocks * 2 * CLUSTERS * sizeof(float2));
    float*  bp      = bl + BATCHES;

    hipMemsetAsync(oseg, 0, NSEG * 2 * sizeof(float), stream);    // ws re-poisoned every call

    mfma_accum_kernel<<<nblocks, BLOCK, 0, stream>>>(
        reco, target, clabel, batch_index, scratch, b0_arr, oseg, n);
    batch_reduce_kernel<<<BATCHES, SLICES * CLUSTERS, 0, stream>>>(
        scratch, b0_arr, oseg, bl, bp, nblocks);
    final_kernel<<<1, 64, 0, stream>>>(bl, bp, (float*)d_out);
}